// Round 10
// baseline (37.894 us; speedup 1.0000x reference)
//
#include <hip/hip_runtime.h>

// Deimv2LQE: out = scores + MLP(top4-softmax-stats(pred_corners))
// 262144 rows; per row 132 f32 (4 corners x 33 bins).
// R10: persistent double-buffered pipeline.
//   512 blocks (2/CU resident, LDS-capped), 8 groups of 64 rows each.
//   Group g+1 staged via global_load_lds (16B DMA, no VGPR round trip)
//   WHILE group g computes. Mid-loop barriers are raw lgkmcnt-only
//   (must not drain vmcnt -> prefetch stays in flight); the end-of-iter
//   __syncthreads (+explicit vmcnt(0)) is where the DMA lands.
//   Compute = R9 (ILP top-4, 4-acc exp, wave-split s_load MLP).

#define THREADS 256
#define GROUPS 8
#define GROUP_ROWS 64

typedef float f32x4 __attribute__((ext_vector_type(4), aligned(16)));

// LDS-only barrier: do NOT drain vmcnt (keeps DMA prefetch in flight)
#define BAR_LGKM() asm volatile("s_waitcnt lgkmcnt(0)\n\ts_barrier" ::: "memory")

__device__ __forceinline__ void gll16(const float* g, float* l) {
    __builtin_amdgcn_global_load_lds(
        (const __attribute__((address_space(1))) void*)g,
        (__attribute__((address_space(3))) void*)l, 16, 0, 0);
}

__device__ __forceinline__ void sort4d(float& a, float& b, float& c, float& d) {
    float t;
    t = fmaxf(a, b); b = fminf(a, b); a = t;
    t = fmaxf(c, d); d = fminf(c, d); c = t;
    t = fmaxf(a, c); c = fminf(a, c); a = t;
    t = fmaxf(b, d); d = fminf(b, d); b = t;
    t = fmaxf(b, c); c = fminf(b, c); b = t;
}
__device__ __forceinline__ void ins4(float& a, float& b, float& c, float& d,
                                     float x) {
    float t;
    t = fmaxf(a, x); x = fminf(a, x); a = t;
    t = fmaxf(b, x); x = fminf(b, x); b = t;
    t = fmaxf(c, x); x = fminf(c, x); c = t;
    d = fmaxf(d, x);
}
__device__ __forceinline__ void merge4(float& a0, float& a1, float& a2,
                                       float& a3, float b0, float b1,
                                       float b2, float b3) {
    a0 = fmaxf(a0, b3);
    a1 = fmaxf(a1, b2);
    a2 = fmaxf(a2, b1);
    a3 = fmaxf(a3, b0);
    sort4d(a0, a1, a2, a3);
}

__global__ __launch_bounds__(THREADS, 2)
void lqe_kernel(const float* __restrict__ scores,
                const float* __restrict__ pc,
                const float* __restrict__ w1,
                const float* __restrict__ b1,
                const float* __restrict__ w2,
                const float* __restrict__ b2,
                float* __restrict__ out)
{
    __shared__ float smA[GROUP_ROWS * 132];   // 33792 B (also partial scratch)
    __shared__ float smB[GROUP_ROWS * 132];   // 33792 B
    __shared__ float smStat[GROUP_ROWS * 21]; // 5376 B, stride 21 (odd)

    const int t = threadIdx.x;
    const int l = t & 63;
    const long long blockRow0 = (long long)blockIdx.x * (GROUPS * GROUP_ROWS);
    const float b2v = b2[0];

    // DMA one 64-row group into buf: 2112 f4; per wave 8 calls + 1 tail.
    auto stage_async = [&](int g, float* buf) {
        const float* src = pc + (blockRow0 + (long long)g * GROUP_ROWS) * 132;
        const int wvOff = __builtin_amdgcn_readfirstlane(t >> 6) * 64; // uniform
        #pragma unroll
        for (int i = 0; i < 8; ++i)
            gll16(src + (size_t)(i * 256 + wvOff + l) * 4,
                  buf + (size_t)(i * 256 + wvOff) * 4);
        if (t < 64)
            gll16(src + (size_t)(2048 + l) * 4, buf + (size_t)2048 * 4);
    };

    // corner task t: row=t>>2, corner=t&3; LDS base 33*t (odd stride, free)
    auto corner = [&](const float* buf) {
        const float* v = buf + t * 33;
        float x[33];
        #pragma unroll
        for (int k = 0; k < 33; ++k) x[k] = v[k];

        float a0 = x[0],  a1 = x[1],  a2 = x[2],  a3 = x[3];
        float c0 = x[8],  c1 = x[9],  c2 = x[10], c3 = x[11];
        float d0 = x[16], d1 = x[17], d2 = x[18], d3 = x[19];
        float e0 = x[24], e1 = x[25], e2 = x[26], e3 = x[27];
        sort4d(a0, a1, a2, a3);
        sort4d(c0, c1, c2, c3);
        sort4d(d0, d1, d2, d3);
        sort4d(e0, e1, e2, e3);
        #pragma unroll
        for (int k = 0; k < 4; ++k) {
            ins4(a0, a1, a2, a3, x[4 + k]);
            ins4(c0, c1, c2, c3, x[12 + k]);
            ins4(d0, d1, d2, d3, x[20 + k]);
            ins4(e0, e1, e2, e3, x[28 + k]);
        }
        ins4(e0, e1, e2, e3, x[32]);
        merge4(a0, a1, a2, a3, c0, c1, c2, c3);
        merge4(d0, d1, d2, d3, e0, e1, e2, e3);
        merge4(a0, a1, a2, a3, d0, d1, d2, d3);
        const float t0 = a0, t1 = a1, t2 = a2, t3 = a3;

        float sa = 0.f, sb = 0.f, sc = 0.f, sd = 0.f;
        #pragma unroll
        for (int k = 0; k < 32; k += 4) {
            sa += __expf(x[k + 0] - t0);
            sb += __expf(x[k + 1] - t0);
            sc += __expf(x[k + 2] - t0);
            sd += __expf(x[k + 3] - t0);
        }
        sa += __expf(x[32] - t0);
        const float inv = 1.0f / ((sa + sb) + (sc + sd));
        const float p0 = inv;
        const float p1 = __expf(t1 - t0) * inv;
        const float p2 = __expf(t2 - t0) * inv;
        const float p3 = __expf(t3 - t0) * inv;
        const float pm = 0.25f * (p0 + p1 + p2 + p3);

        float* sd_ = smStat + (t >> 2) * 21 + (t & 3) * 5;
        sd_[0] = p0; sd_[1] = p1; sd_[2] = p2; sd_[3] = p3; sd_[4] = pm;
    };

    // wave-split MLP: wave wv -> hidden slice [16wv,16wv+16), lane = row
    auto mlp = [&](float* buf) {
        const int wv = __builtin_amdgcn_readfirstlane(t >> 6);
        const float* __restrict__ w1s = w1 + wv * 16;
        const float* __restrict__ w2s = w2 + wv * 16;
        const float* __restrict__ b1s = b1 + wv * 16;

        float st[20];
        #pragma unroll
        for (int k = 0; k < 20; ++k) st[k] = smStat[l * 21 + k];

        float h[16];
        #pragma unroll
        for (int j = 0; j < 16; ++j) h[j] = b1s[j];
        #pragma unroll
        for (int k = 0; k < 20; ++k) {
            #pragma unroll
            for (int j = 0; j < 16; ++j)
                h[j] = fmaf(st[k], w1s[k * 64 + j], h[j]);
        }
        float acc0 = 0.f, acc1 = 0.f, acc2 = 0.f, acc3 = 0.f;
        #pragma unroll
        for (int j = 0; j < 16; j += 4) {
            acc0 = fmaf(fmaxf(h[j + 0], 0.f), w2s[j + 0], acc0);
            acc1 = fmaf(fmaxf(h[j + 1], 0.f), w2s[j + 1], acc1);
            acc2 = fmaf(fmaxf(h[j + 2], 0.f), w2s[j + 2], acc2);
            acc3 = fmaf(fmaxf(h[j + 3], 0.f), w2s[j + 3], acc3);
        }
        buf[wv * 64 + l] = (acc0 + acc1) + (acc2 + acc3);
    };

    // prologue
    stage_async(0, smA);
    __syncthreads();

    #pragma unroll 1
    for (int gp = 0; gp < GROUPS; gp += 2) {
        // ---------- even: cur = smA, nxt = smB ----------
        {
            float sc0 = 0.f;
            if (t < 64) sc0 = scores[blockRow0 + (long long)gp * 64 + t]; // before DMA -> vmcnt(9) wait
            if (gp + 1 < GROUPS) stage_async(gp + 1, smB);
            corner(smA);
            BAR_LGKM();                 // stats visible; DMA stays in flight
            mlp(smA);
            BAR_LGKM();
            if (t < 64)
                out[blockRow0 + (long long)gp * 64 + t] =
                    sc0 + (smA[t] + smA[64 + t]) + (smA[128 + t] + smA[192 + t]) + b2v;
            asm volatile("s_waitcnt vmcnt(0)" ::: "memory"); // DMA landed
            __syncthreads();
        }
        // ---------- odd: cur = smB, nxt = smA ----------
        {
            float sc1 = 0.f;
            if (t < 64) sc1 = scores[blockRow0 + (long long)(gp + 1) * 64 + t];
            if (gp + 2 < GROUPS) stage_async(gp + 2, smA);
            corner(smB);
            BAR_LGKM();
            mlp(smB);
            BAR_LGKM();
            if (t < 64)
                out[blockRow0 + (long long)(gp + 1) * 64 + t] =
                    sc1 + (smB[t] + smB[64 + t]) + (smB[128 + t] + smB[192 + t]) + b2v;
            asm volatile("s_waitcnt vmcnt(0)" ::: "memory");
            __syncthreads();
        }
    }
}

extern "C" void kernel_launch(void* const* d_in, const int* in_sizes, int n_in,
                              void* d_out, int out_size, void* d_ws, size_t ws_size,
                              hipStream_t stream) {
    const float* scores = (const float*)d_in[0];
    const float* pc     = (const float*)d_in[1];
    const float* w1     = (const float*)d_in[2];
    const float* b1     = (const float*)d_in[3];
    const float* w2     = (const float*)d_in[4];
    const float* b2     = (const float*)d_in[5];
    float* out = (float*)d_out;

    const int rows = out_size;                      // 262144
    const int blocks = rows / (GROUPS * GROUP_ROWS); // 512
    lqe_kernel<<<blocks, THREADS, 0, stream>>>(scores, pc, w1, b1, w2, b2, out);
}

// Round 11
// 33.602 us; speedup vs baseline: 1.1277x; 1.1277x over previous
//
#include <hip/hip_runtime.h>

// Deimv2LQE: out = scores + MLP(top4-softmax-stats(pred_corners))
// 262144 rows; per row 132 f32 (4 corners x 33 bins).
// R11 = R9 (best: 32.7us) with WAVE-PRIVATE staging to break the barrier
//   convoy: each wave stages its own 16 rows (528 contiguous float4,
//   coalesced within the wave) into its private LDS slice and proceeds
//   straight to corner compute with NO barrier (within-wave DS ordering).
//   The 4 waves' VMEM waits stagger instead of convoying at a block-wide
//   vmcnt(0) barrier; independent streams/CU: 4 blocks -> 16 waves.
//   Barriers 3 -> 2. Corner compute (ILP top-4) and wave-split s_load MLP
//   unchanged from R9.

#define THREADS 256
#define ROWS 64

typedef float f32x4 __attribute__((ext_vector_type(4), aligned(16)));

__device__ __forceinline__ void sort4d(float& a, float& b, float& c, float& d) {
    float t;
    t = fmaxf(a, b); b = fminf(a, b); a = t;
    t = fmaxf(c, d); d = fminf(c, d); c = t;
    t = fmaxf(a, c); c = fminf(a, c); a = t;
    t = fmaxf(b, d); d = fminf(b, d); b = t;
    t = fmaxf(b, c); c = fminf(b, c); b = t;
}
__device__ __forceinline__ void ins4(float& a, float& b, float& c, float& d,
                                     float x) {
    float t;
    t = fmaxf(a, x); x = fminf(a, x); a = t;
    t = fmaxf(b, x); x = fminf(b, x); b = t;
    t = fmaxf(c, x); x = fminf(c, x); c = t;
    d = fmaxf(d, x);
}
__device__ __forceinline__ void merge4(float& a0, float& a1, float& a2,
                                       float& a3, float b0, float b1,
                                       float b2, float b3) {
    a0 = fmaxf(a0, b3);
    a1 = fmaxf(a1, b2);
    a2 = fmaxf(a2, b1);
    a3 = fmaxf(a3, b0);
    sort4d(a0, a1, a2, a3);
}

__global__ __launch_bounds__(THREADS, 4)
void lqe_kernel(const float* __restrict__ scores,
                const float* __restrict__ pc,
                const float* __restrict__ w1,
                const float* __restrict__ b1,
                const float* __restrict__ w2,
                const float* __restrict__ b2,
                float* __restrict__ out)
{
    __shared__ float smStage[ROWS * 132];  // 33792 B; per-wave 2112-f slices
    __shared__ float smStat[ROWS * 21];    // 5376 B, stride 21 (odd)

    const int t  = threadIdx.x;
    const int wv = t >> 6;
    const int l  = t & 63;
    const long long rowBase = (long long)blockIdx.x * ROWS;

    float sc = 0.f;
    if (t < 64) sc = scores[rowBase + t];   // issued first, deep in queue

    // ---- wave-private stage: 528 contiguous f4 per wave, coalesced ----
    {
        const f32x4* __restrict__ src =
            (const f32x4*)(pc + rowBase * 132) + wv * 528;
        f32x4* dst = (f32x4*)smStage + wv * 528;
        #pragma unroll
        for (int i = 0; i < 8; ++i) dst[l + i * 64] = src[l + i * 64];
        if (l < 16) dst[512 + l] = src[512 + l];
    }

    // ---- corner task (wave-private, NO barrier): row = 16wv + (l>>2),
    //      corner = l&3; LDS base = wv*2112 + 33*l (odd stride, free) ----
    {
        const float* v = smStage + wv * 2112 + l * 33;
        float x[33];
        #pragma unroll
        for (int k = 0; k < 33; ++k) x[k] = v[k];

        float a0 = x[0],  a1 = x[1],  a2 = x[2],  a3 = x[3];
        float c0 = x[8],  c1 = x[9],  c2 = x[10], c3 = x[11];
        float d0 = x[16], d1 = x[17], d2 = x[18], d3 = x[19];
        float e0 = x[24], e1 = x[25], e2 = x[26], e3 = x[27];
        sort4d(a0, a1, a2, a3);
        sort4d(c0, c1, c2, c3);
        sort4d(d0, d1, d2, d3);
        sort4d(e0, e1, e2, e3);
        #pragma unroll
        for (int k = 0; k < 4; ++k) {
            ins4(a0, a1, a2, a3, x[4 + k]);
            ins4(c0, c1, c2, c3, x[12 + k]);
            ins4(d0, d1, d2, d3, x[20 + k]);
            ins4(e0, e1, e2, e3, x[28 + k]);
        }
        ins4(e0, e1, e2, e3, x[32]);
        merge4(a0, a1, a2, a3, c0, c1, c2, c3);
        merge4(d0, d1, d2, d3, e0, e1, e2, e3);
        merge4(a0, a1, a2, a3, d0, d1, d2, d3);
        const float t0 = a0, t1 = a1, t2 = a2, t3 = a3;

        float sa = 0.f, sb = 0.f, scc = 0.f, sd = 0.f;
        #pragma unroll
        for (int k = 0; k < 32; k += 4) {
            sa  += __expf(x[k + 0] - t0);
            sb  += __expf(x[k + 1] - t0);
            scc += __expf(x[k + 2] - t0);
            sd  += __expf(x[k + 3] - t0);
        }
        sa += __expf(x[32] - t0);
        const float inv = 1.0f / ((sa + sb) + (scc + sd));
        const float p0 = inv;
        const float p1 = __expf(t1 - t0) * inv;
        const float p2 = __expf(t2 - t0) * inv;
        const float p3 = __expf(t3 - t0) * inv;
        const float pm = 0.25f * (p0 + p1 + p2 + p3);

        float* sd_ = smStat + (wv * 16 + (l >> 2)) * 21 + (l & 3) * 5;
        sd_[0] = p0; sd_[1] = p1; sd_[2] = p2; sd_[3] = p3; sd_[4] = pm;
    }
    __syncthreads();   // stats of all waves visible

    // ---- MLP: wave wv -> hidden slice [16wv,16wv+16), lane = row ----
    {
        const int wvs = __builtin_amdgcn_readfirstlane(wv);  // scalar
        const float* __restrict__ w1s = w1 + wvs * 16;
        const float* __restrict__ w2s = w2 + wvs * 16;
        const float* __restrict__ b1s = b1 + wvs * 16;

        float st[20];
        #pragma unroll
        for (int k = 0; k < 20; ++k) st[k] = smStat[l * 21 + k];

        float h[16];
        #pragma unroll
        for (int j = 0; j < 16; ++j) h[j] = b1s[j];
        #pragma unroll
        for (int k = 0; k < 20; ++k) {
            #pragma unroll
            for (int j = 0; j < 16; ++j)
                h[j] = fmaf(st[k], w1s[k * 64 + j], h[j]);
        }
        float acc0 = 0.f, acc1 = 0.f, acc2 = 0.f, acc3 = 0.f;
        #pragma unroll
        for (int j = 0; j < 16; j += 4) {
            acc0 = fmaf(fmaxf(h[j + 0], 0.f), w2s[j + 0], acc0);
            acc1 = fmaf(fmaxf(h[j + 1], 0.f), w2s[j + 1], acc1);
            acc2 = fmaf(fmaxf(h[j + 2], 0.f), w2s[j + 2], acc2);
            acc3 = fmaf(fmaxf(h[j + 3], 0.f), w2s[j + 3], acc3);
        }
        // partials into the (now dead) stage region
        smStage[wvs * 64 + l] = (acc0 + acc1) + (acc2 + acc3);
    }
    __syncthreads();

    // ---- reduce 4 partials, add score, coalesced store ----
    if (t < 64) {
        const float r = (smStage[t] + smStage[64 + t]) +
                        (smStage[128 + t] + smStage[192 + t]);
        out[rowBase + t] = sc + r + b2[0];
    }
}

extern "C" void kernel_launch(void* const* d_in, const int* in_sizes, int n_in,
                              void* d_out, int out_size, void* d_ws, size_t ws_size,
                              hipStream_t stream) {
    const float* scores = (const float*)d_in[0];
    const float* pc     = (const float*)d_in[1];
    const float* w1     = (const float*)d_in[2];
    const float* b1     = (const float*)d_in[3];
    const float* w2     = (const float*)d_in[4];
    const float* b2     = (const float*)d_in[5];
    float* out = (float*)d_out;

    const int rows = out_size;          // 262144
    const int blocks = rows / ROWS;     // 4096
    lqe_kernel<<<blocks, THREADS, 0, stream>>>(scores, pc, w1, b1, w2, b2, out);
}